// Round 2
// baseline (978.150 us; speedup 1.0000x reference)
//
#include <hip/hip_runtime.h>
#include <hip/hip_bf16.h>
#include <math.h>

#define TT 32
#define NN 2048
#define FF 64

typedef float f32x4 __attribute__((ext_vector_type(4)));

// ---------------------------------------------------------------------------
// K_A: per-timestep scores (fp64) + top-64 (desc, min-index tie-break) +
// z^T[t][j][f] = X[idx_j][f] * tanh(val_j).  grid = T, 256 threads.
// ---------------------------------------------------------------------------
__global__ __launch_bounds__(256) void topk_kernel(
    const float* __restrict__ X, const float* __restrict__ mask,
    const float* __restrict__ scorer, float* __restrict__ zt)
{
    const int t = blockIdx.x, tid = threadIdx.x;
    __shared__ double svals[64];
    __shared__ int    sidx[64];
    __shared__ double swv[4];
    __shared__ int    swi[4];

    float sc[64];
#pragma unroll
    for (int f = 0; f < 64; f += 4) {
        float4 v = *(const float4*)(scorer + f);
        sc[f] = v.x; sc[f+1] = v.y; sc[f+2] = v.z; sc[f+3] = v.w;
    }
    double nrm = 0.0;
#pragma unroll
    for (int f = 0; f < 64; ++f) nrm += (double)sc[f] * (double)sc[f];
    const double inv = 1.0 / sqrt(nrm);

    const float* Xt = X + (size_t)t * NN * FF;
    double ls[8];
#pragma unroll
    for (int e = 0; e < 8; ++e) {
        const int n = e * 256 + tid;
        const float* xr = Xt + (size_t)n * FF;
        double s = 0.0;
#pragma unroll
        for (int f = 0; f < 64; f += 4) {
            float4 v = *(const float4*)(xr + f);
            s += (double)v.x * (double)sc[f]   + (double)v.y * (double)sc[f+1]
               + (double)v.z * (double)sc[f+2] + (double)v.w * (double)sc[f+3];
        }
        ls[e] = s * inv + (double)mask[t * NN + n];
    }

    const int lane = tid & 63, w = tid >> 6;
    for (int r = 0; r < 64; ++r) {
        double bv = ls[0]; int bi = tid;
#pragma unroll
        for (int e = 1; e < 8; ++e) {
            const int n = e * 256 + tid;
            if (ls[e] > bv) { bv = ls[e]; bi = n; }
        }
#pragma unroll
        for (int off = 1; off < 64; off <<= 1) {
            double ov = __shfl_xor(bv, off);
            int    oi = __shfl_xor(bi, off);
            if (ov > bv || (ov == bv && oi < bi)) { bv = ov; bi = oi; }
        }
        if (lane == 0) { swv[w] = bv; swi[w] = bi; }
        __syncthreads();
        if (tid == 0) {
            double fv = swv[0]; int fi = swi[0];
#pragma unroll
            for (int q = 1; q < 4; ++q)
                if (swv[q] > fv || (swv[q] == fv && swi[q] < fi)) { fv = swv[q]; fi = swi[q]; }
            svals[r] = fv; sidx[r] = fi;
        }
        __syncthreads();
        const int win = sidx[r];
#pragma unroll
        for (int e = 0; e < 8; ++e)
            if (win == e * 256 + tid) ls[e] = -INFINITY;
    }
    __syncthreads();

    const int j = tid >> 2, fg = tid & 3;
    const float th  = tanhf((float)svals[j]);
    const int  idx  = sidx[j];
    const float* xr = Xt + (size_t)idx * FF + fg * 16;
    float* zr = zt + (size_t)t * 4096 + j * 64 + fg * 16;
#pragma unroll
    for (int f = 0; f < 16; f += 4) {
        float4 v = *(const float4*)(xr + f);
        *(float4*)(zr + f) = make_float4(v.x * th, v.y * th, v.z * th, v.w * th);
    }
}

// ---------------------------------------------------------------------------
// K_W: Wz[m][t][i][j] = b_m[i][j] + sum_f W_m[i][f] * z[f][j]
// ---------------------------------------------------------------------------
__global__ __launch_bounds__(256) void wz_kernel(
    const float* __restrict__ zt,
    const float* __restrict__ Wu, const float* __restrict__ bu,
    const float* __restrict__ Wr, const float* __restrict__ br,
    const float* __restrict__ Wh, const float* __restrict__ bh,
    float* __restrict__ Wz)
{
    const int m = blockIdx.x, t = blockIdx.y, tid = threadIdx.x;
    const float* W = (m == 0) ? Wu : (m == 1) ? Wr : Wh;
    const float* b = (m == 0) ? bu : (m == 1) ? br : bh;
    const int j = tid & 63, i0 = (tid >> 6) << 4;

    float zr[64];
    const float* zrow = zt + (size_t)t * 4096 + j * 64;
#pragma unroll
    for (int f = 0; f < 64; f += 4) {
        float4 v = *(const float4*)(zrow + f);
        zr[f] = v.x; zr[f+1] = v.y; zr[f+2] = v.z; zr[f+3] = v.w;
    }
    float* o = Wz + ((size_t)m * TT + t) * 4096;
    for (int i = i0; i < i0 + 16; ++i) {
        float acc = b[i * 64 + j];
#pragma unroll
        for (int f = 0; f < 64; ++f) acc += W[i * 64 + f] * zr[f];
        o[i * 64 + j] = acc;
    }
}

// ---------------------------------------------------------------------------
// K_B: column-separable GRU chain, one Q-column per block.
// ---------------------------------------------------------------------------
__global__ __launch_bounds__(256) void qchain_kernel(
    const float* __restrict__ Q0,
    const float* __restrict__ Uu, const float* __restrict__ Ur, const float* __restrict__ Uh,
    const float* __restrict__ Wz, float* __restrict__ Qseq)
{
    const int j = blockIdx.x, tid = threadIdx.x;
    const int w = tid >> 6, l = tid & 63;
    const int i = (w << 4) + (l & 15);
    const int fq = l >> 4, fb = fq << 4;

    float uu[16], ur[16], uh[16];
#pragma unroll
    for (int e = 0; e < 16; e += 4) {
        float4 a = *(const float4*)(Uu + i * 64 + fb + e);
        uu[e] = a.x; uu[e+1] = a.y; uu[e+2] = a.z; uu[e+3] = a.w;
        float4 c = *(const float4*)(Ur + i * 64 + fb + e);
        ur[e] = c.x; ur[e+1] = c.y; ur[e+2] = c.z; ur[e+3] = c.w;
        float4 d = *(const float4*)(Uh + i * 64 + fb + e);
        uh[e] = d.x; uh[e+1] = d.y; uh[e+2] = d.z; uh[e+3] = d.w;
    }
    __shared__ __align__(16) float q[64];
    __shared__ __align__(16) float rr[64];
    if (tid < 64) q[tid] = Q0[tid * 64 + j];
    __syncthreads();

    const float* WzU = Wz;
    const float* WzR = Wz + (size_t)TT * 4096;
    const float* WzH = Wz + (size_t)2 * TT * 4096;

    for (int t = 0; t < TT; ++t) {
        float q16[16];
#pragma unroll
        for (int e = 0; e < 16; e += 4) {
            f32x4 v = *(const f32x4*)(&q[fb + e]);
            q16[e] = v[0]; q16[e+1] = v[1]; q16[e+2] = v[2]; q16[e+3] = v[3];
        }
        float su = 0.f, sr = 0.f;
#pragma unroll
        for (int e = 0; e < 16; ++e) { su += uu[e] * q16[e]; sr += ur[e] * q16[e]; }
        su += __shfl_xor(su, 16); su += __shfl_xor(su, 32);
        sr += __shfl_xor(sr, 16); sr += __shfl_xor(sr, 32);
        const int off = t * 4096 + i * 64 + j;
        const float u_ = 1.f / (1.f + expf(-(su + WzU[off])));
        const float r_ = 1.f / (1.f + expf(-(sr + WzR[off])));
        if (fq == 0) rr[i] = r_;
        __syncthreads();
        float sh = 0.f;
#pragma unroll
        for (int e = 0; e < 16; e += 4) {
            f32x4 v = *(const f32x4*)(&rr[fb + e]);
            sh += uh[e]   * (v[0] * q16[e]);
            sh += uh[e+1] * (v[1] * q16[e+1]);
            sh += uh[e+2] * (v[2] * q16[e+2]);
            sh += uh[e+3] * (v[3] * q16[e+3]);
        }
        sh += __shfl_xor(sh, 16); sh += __shfl_xor(sh, 32);
        float hv = sh + WzH[off];
        hv = hv > 0.f ? hv : 0.f;
        const float qi = q[i];
        const float qn = (1.f - u_) * qi + u_ * hv;
        __syncthreads();
        if (fq == 0) {
            q[i] = qn;
            Qseq[(size_t)t * 4096 + i * 64 + j] = qn;
        }
        __syncthreads();
    }
}

// ---------------------------------------------------------------------------
// K_C: Ytf[t][j][n] = sum_f X[t][n][f] * Qseq[t][f][j]   (fp32)
// ---------------------------------------------------------------------------
__global__ __launch_bounds__(256) void y_kernel(
    const float* __restrict__ X, const float* __restrict__ Qseq,
    float* __restrict__ Ytf)
{
    const int t = blockIdx.y, tid = threadIdx.x;
    const int n = blockIdx.x * 256 + tid;
    __shared__ __align__(16) float Qs[4096];
    for (int c = tid; c < 4096; c += 256) Qs[c] = Qseq[(size_t)t * 4096 + c];
    __syncthreads();

    const float* xr = X + ((size_t)t * NN + n) * FF;
    float y[64];
#pragma unroll
    for (int jj = 0; jj < 64; ++jj) y[jj] = 0.f;
    for (int f4 = 0; f4 < 64; f4 += 4) {
        float4 xv = *(const float4*)(xr + f4);
        float xa[4] = {xv.x, xv.y, xv.z, xv.w};
#pragma unroll
        for (int ff = 0; ff < 4; ++ff) {
            const float xf = xa[ff];
            const float* qr = &Qs[(f4 + ff) << 6];
#pragma unroll
            for (int jj = 0; jj < 64; jj += 4) {
                f32x4 qv = *(const f32x4*)(qr + jj);
                y[jj]   += xf * qv[0];
                y[jj+1] += xf * qv[1];
                y[jj+2] += xf * qv[2];
                y[jj+3] += xf * qv[3];
            }
        }
    }
    float* yo = Ytf + (size_t)t * FF * NN + n;
#pragma unroll
    for (int jj = 0; jj < 64; ++jj) yo[(size_t)jj * NN] = y[jj];
}

// ---------------------------------------------------------------------------
// K_D: out[t] = relu(A[t] @ Y[t]) — fp32 VALU GEMM (bisect round).
// grid = (N/64, T), 256 threads; block tile 64x64, BK=64, micro 4x4.
// LDS rows XOR-swizzled so stride-4-row f32x4 reads are conflict-free.
// ---------------------------------------------------------------------------
__global__ __launch_bounds__(256) void gemm_f32_kernel(
    const float* __restrict__ A, const float* __restrict__ Ytf,
    float* __restrict__ out)
{
    __shared__ __align__(16) float As[64 * 64];
    __shared__ __align__(16) float Ys[64 * 64];
    const int t = blockIdx.y, tid = threadIdx.x;
    const int m0 = blockIdx.x * 64;
    const int ri = tid >> 4, ci = tid & 15;

    const float* Ap = A + (size_t)t * NN * NN + (size_t)m0 * NN;
    const float* Yp = Ytf + (size_t)t * FF * NN;

    float acc[4][4];
#pragma unroll
    for (int ii = 0; ii < 4; ++ii)
#pragma unroll
        for (int jj = 0; jj < 4; ++jj) acc[ii][jj] = 0.f;

    for (int kk = 0; kk < NN; kk += 64) {
        __syncthreads();
#pragma unroll
        for (int it = 0; it < 4; ++it) {
            const int c = tid + it * 256;
            const int r = c >> 4, c4 = (c & 15) << 2;
            const int sw = ((r >> 2) & 7) << 2;
            *(f32x4*)&As[r * 64 + (c4 ^ sw)] = *(const f32x4*)(Ap + (size_t)r * NN + kk + c4);
            *(f32x4*)&Ys[r * 64 + (c4 ^ sw)] = *(const f32x4*)(Yp + (size_t)r * NN + kk + c4);
        }
        __syncthreads();
#pragma unroll
        for (int k = 0; k < 64; k += 4) {
            f32x4 a[4], b[4];
#pragma unroll
            for (int ii = 0; ii < 4; ++ii) {
                const int r = (ri << 2) + ii;
                a[ii] = *(const f32x4*)&As[r * 64 + (k ^ (((r >> 2) & 7) << 2))];
            }
#pragma unroll
            for (int jj = 0; jj < 4; ++jj) {
                const int r = (ci << 2) + jj;
                b[jj] = *(const f32x4*)&Ys[r * 64 + (k ^ (((r >> 2) & 7) << 2))];
            }
#pragma unroll
            for (int ii = 0; ii < 4; ++ii)
#pragma unroll
                for (int jj = 0; jj < 4; ++jj)
                    acc[ii][jj] += a[ii][0] * b[jj][0] + a[ii][1] * b[jj][1]
                                 + a[ii][2] * b[jj][2] + a[ii][3] * b[jj][3];
        }
    }
#pragma unroll
    for (int ii = 0; ii < 4; ++ii) {
        f32x4 o;
#pragma unroll
        for (int jj = 0; jj < 4; ++jj) {
            const float v = acc[ii][jj];
            o[jj] = v > 0.f ? v : 0.f;
        }
        *(f32x4*)(out + ((size_t)t * NN + m0 + (ri << 2) + ii) * FF + (ci << 2)) = o;
    }
}

// ---------------------------------------------------------------------------
extern "C" void kernel_launch(void* const* d_in, const int* in_sizes, int n_in,
                              void* d_out, int out_size, void* d_ws, size_t ws_size,
                              hipStream_t stream) {
    const float* A      = (const float*)d_in[0];
    const float* X      = (const float*)d_in[1];
    const float* mask   = (const float*)d_in[2];
    const float* Q0     = (const float*)d_in[3];
    const float* scorer = (const float*)d_in[4];
    const float* Wu     = (const float*)d_in[5];
    const float* Uu     = (const float*)d_in[6];
    const float* bu     = (const float*)d_in[7];
    const float* Wr     = (const float*)d_in[8];
    const float* Ur     = (const float*)d_in[9];
    const float* br     = (const float*)d_in[10];
    const float* Wh     = (const float*)d_in[11];
    const float* Uh     = (const float*)d_in[12];
    const float* bh     = (const float*)d_in[13];
    float* out = (float*)d_out;

    float* ws   = (float*)d_ws;
    float* zt   = ws;              // [T][64][64]
    float* Wz   = ws + 131072;     // [3][T][64][64]
    float* Qseq = ws + 524288;     // [T][64][64]
    float* Ytf  = ws + 655360;     // [T][64][2048] fp32

    topk_kernel<<<TT, 256, 0, stream>>>(X, mask, scorer, zt);
    wz_kernel<<<dim3(3, TT), 256, 0, stream>>>(zt, Wu, bu, Wr, br, Wh, bh, Wz);
    qchain_kernel<<<FF, 256, 0, stream>>>(Q0, Uu, Ur, Uh, Wz, Qseq);
    y_kernel<<<dim3(NN / 256, TT), 256, 0, stream>>>(X, Qseq, Ytf);
    gemm_f32_kernel<<<dim3(NN / 64, TT), 256, 0, stream>>>(A, Ytf, out);
}

// Round 3
// 324.032 us; speedup vs baseline: 3.0187x; 3.0187x over previous
//
#include <hip/hip_runtime.h>
#include <hip/hip_bf16.h>
#include <math.h>

#define TT 32
#define NN 2048
#define FF 64

typedef float f32x4 __attribute__((ext_vector_type(4)));
typedef __bf16 bf16x8 __attribute__((ext_vector_type(8)));

__device__ __forceinline__ unsigned short f2bf(float f) {
    __bf16 h = (__bf16)f;
    return __builtin_bit_cast(unsigned short, h);
}

// ---------------------------------------------------------------------------
// K_A: per-timestep scores (fp64) + top-64 (desc, min-index tie-break) +
// z^T[t][j][f] = X[idx_j][f] * tanh(val_j).  grid = T, 256 threads.
// ---------------------------------------------------------------------------
__global__ __launch_bounds__(256) void topk_kernel(
    const float* __restrict__ X, const float* __restrict__ mask,
    const float* __restrict__ scorer, float* __restrict__ zt)
{
    const int t = blockIdx.x, tid = threadIdx.x;
    __shared__ double svals[64];
    __shared__ int    sidx[64];
    __shared__ double swv[4];
    __shared__ int    swi[4];

    float sc[64];
#pragma unroll
    for (int f = 0; f < 64; f += 4) {
        float4 v = *(const float4*)(scorer + f);
        sc[f] = v.x; sc[f+1] = v.y; sc[f+2] = v.z; sc[f+3] = v.w;
    }
    double nrm = 0.0;
#pragma unroll
    for (int f = 0; f < 64; ++f) nrm += (double)sc[f] * (double)sc[f];
    const double inv = 1.0 / sqrt(nrm);

    const float* Xt = X + (size_t)t * NN * FF;
    double ls[8];
#pragma unroll
    for (int e = 0; e < 8; ++e) {
        const int n = e * 256 + tid;
        const float* xr = Xt + (size_t)n * FF;
        double s = 0.0;
#pragma unroll
        for (int f = 0; f < 64; f += 4) {
            float4 v = *(const float4*)(xr + f);
            s += (double)v.x * (double)sc[f]   + (double)v.y * (double)sc[f+1]
               + (double)v.z * (double)sc[f+2] + (double)v.w * (double)sc[f+3];
        }
        ls[e] = s * inv + (double)mask[t * NN + n];
    }

    const int lane = tid & 63, w = tid >> 6;
    for (int r = 0; r < 64; ++r) {
        double bv = ls[0]; int bi = tid;
#pragma unroll
        for (int e = 1; e < 8; ++e) {
            const int n = e * 256 + tid;
            if (ls[e] > bv) { bv = ls[e]; bi = n; }
        }
#pragma unroll
        for (int off = 1; off < 64; off <<= 1) {
            double ov = __shfl_xor(bv, off);
            int    oi = __shfl_xor(bi, off);
            if (ov > bv || (ov == bv && oi < bi)) { bv = ov; bi = oi; }
        }
        if (lane == 0) { swv[w] = bv; swi[w] = bi; }
        __syncthreads();
        if (tid == 0) {
            double fv = swv[0]; int fi = swi[0];
#pragma unroll
            for (int q = 1; q < 4; ++q)
                if (swv[q] > fv || (swv[q] == fv && swi[q] < fi)) { fv = swv[q]; fi = swi[q]; }
            svals[r] = fv; sidx[r] = fi;
        }
        __syncthreads();
        const int win = sidx[r];
#pragma unroll
        for (int e = 0; e < 8; ++e)
            if (win == e * 256 + tid) ls[e] = -INFINITY;
    }
    __syncthreads();

    const int j = tid >> 2, fg = tid & 3;
    const float th  = tanhf((float)svals[j]);
    const int  idx  = sidx[j];
    const float* xr = Xt + (size_t)idx * FF + fg * 16;
    float* zr = zt + (size_t)t * 4096 + j * 64 + fg * 16;
#pragma unroll
    for (int f = 0; f < 16; f += 4) {
        float4 v = *(const float4*)(xr + f);
        *(float4*)(zr + f) = make_float4(v.x * th, v.y * th, v.z * th, v.w * th);
    }
}

// ---------------------------------------------------------------------------
// K_W: Wz[m][t][i][j] = b_m[i][j] + sum_f W_m[i][f] * z[f][j]
// ---------------------------------------------------------------------------
__global__ __launch_bounds__(256) void wz_kernel(
    const float* __restrict__ zt,
    const float* __restrict__ Wu, const float* __restrict__ bu,
    const float* __restrict__ Wr, const float* __restrict__ br,
    const float* __restrict__ Wh, const float* __restrict__ bh,
    float* __restrict__ Wz)
{
    const int m = blockIdx.x, t = blockIdx.y, tid = threadIdx.x;
    const float* W = (m == 0) ? Wu : (m == 1) ? Wr : Wh;
    const float* b = (m == 0) ? bu : (m == 1) ? br : bh;
    const int j = tid & 63, i0 = (tid >> 6) << 4;

    float zr[64];
    const float* zrow = zt + (size_t)t * 4096 + j * 64;
#pragma unroll
    for (int f = 0; f < 64; f += 4) {
        float4 v = *(const float4*)(zrow + f);
        zr[f] = v.x; zr[f+1] = v.y; zr[f+2] = v.z; zr[f+3] = v.w;
    }
    float* o = Wz + ((size_t)m * TT + t) * 4096;
    for (int i = i0; i < i0 + 16; ++i) {
        float acc = b[i * 64 + j];
#pragma unroll
        for (int f = 0; f < 64; ++f) acc += W[i * 64 + f] * zr[f];
        o[i * 64 + j] = acc;
    }
}

// ---------------------------------------------------------------------------
// K_B: column-separable GRU chain, one Q-column per block.
// ---------------------------------------------------------------------------
__global__ __launch_bounds__(256) void qchain_kernel(
    const float* __restrict__ Q0,
    const float* __restrict__ Uu, const float* __restrict__ Ur, const float* __restrict__ Uh,
    const float* __restrict__ Wz, float* __restrict__ Qseq)
{
    const int j = blockIdx.x, tid = threadIdx.x;
    const int w = tid >> 6, l = tid & 63;
    const int i = (w << 4) + (l & 15);
    const int fq = l >> 4, fb = fq << 4;

    float uu[16], ur[16], uh[16];
#pragma unroll
    for (int e = 0; e < 16; e += 4) {
        float4 a = *(const float4*)(Uu + i * 64 + fb + e);
        uu[e] = a.x; uu[e+1] = a.y; uu[e+2] = a.z; uu[e+3] = a.w;
        float4 c = *(const float4*)(Ur + i * 64 + fb + e);
        ur[e] = c.x; ur[e+1] = c.y; ur[e+2] = c.z; ur[e+3] = c.w;
        float4 d = *(const float4*)(Uh + i * 64 + fb + e);
        uh[e] = d.x; uh[e+1] = d.y; uh[e+2] = d.z; uh[e+3] = d.w;
    }
    __shared__ __align__(16) float q[64];
    __shared__ __align__(16) float rr[64];
    if (tid < 64) q[tid] = Q0[tid * 64 + j];
    __syncthreads();

    const float* WzU = Wz;
    const float* WzR = Wz + (size_t)TT * 4096;
    const float* WzH = Wz + (size_t)2 * TT * 4096;

    for (int t = 0; t < TT; ++t) {
        float q16[16];
#pragma unroll
        for (int e = 0; e < 16; e += 4) {
            f32x4 v = *(const f32x4*)(&q[fb + e]);
            q16[e] = v[0]; q16[e+1] = v[1]; q16[e+2] = v[2]; q16[e+3] = v[3];
        }
        float su = 0.f, sr = 0.f;
#pragma unroll
        for (int e = 0; e < 16; ++e) { su += uu[e] * q16[e]; sr += ur[e] * q16[e]; }
        su += __shfl_xor(su, 16); su += __shfl_xor(su, 32);
        sr += __shfl_xor(sr, 16); sr += __shfl_xor(sr, 32);
        const int off = t * 4096 + i * 64 + j;
        const float u_ = 1.f / (1.f + expf(-(su + WzU[off])));
        const float r_ = 1.f / (1.f + expf(-(sr + WzR[off])));
        if (fq == 0) rr[i] = r_;
        __syncthreads();
        float sh = 0.f;
#pragma unroll
        for (int e = 0; e < 16; e += 4) {
            f32x4 v = *(const f32x4*)(&rr[fb + e]);
            sh += uh[e]   * (v[0] * q16[e]);
            sh += uh[e+1] * (v[1] * q16[e+1]);
            sh += uh[e+2] * (v[2] * q16[e+2]);
            sh += uh[e+3] * (v[3] * q16[e+3]);
        }
        sh += __shfl_xor(sh, 16); sh += __shfl_xor(sh, 32);
        float hv = sh + WzH[off];
        hv = hv > 0.f ? hv : 0.f;
        const float qi = q[i];
        const float qn = (1.f - u_) * qi + u_ * hv;
        __syncthreads();
        if (fq == 0) {
            q[i] = qn;
            Qseq[(size_t)t * 4096 + i * 64 + j] = qn;
        }
        __syncthreads();
    }
}

// ---------------------------------------------------------------------------
// K_C: Ytr[t][j][n] = bf16( sum_f X[t][n][f] * Qseq[t][f][j] )
// ---------------------------------------------------------------------------
__global__ __launch_bounds__(256) void y_kernel(
    const float* __restrict__ X, const float* __restrict__ Qseq,
    unsigned short* __restrict__ Ytr)
{
    const int t = blockIdx.y, tid = threadIdx.x;
    const int n = blockIdx.x * 256 + tid;
    __shared__ __align__(16) float Qs[4096];
    for (int c = tid; c < 4096; c += 256) Qs[c] = Qseq[(size_t)t * 4096 + c];
    __syncthreads();

    const float* xr = X + ((size_t)t * NN + n) * FF;
    float y[64];
#pragma unroll
    for (int jj = 0; jj < 64; ++jj) y[jj] = 0.f;
    for (int f4 = 0; f4 < 64; f4 += 4) {
        float4 xv = *(const float4*)(xr + f4);
        float xa[4] = {xv.x, xv.y, xv.z, xv.w};
#pragma unroll
        for (int ff = 0; ff < 4; ++ff) {
            const float xf = xa[ff];
            const float* qr = &Qs[(f4 + ff) << 6];
#pragma unroll
            for (int jj = 0; jj < 64; jj += 4) {
                f32x4 qv = *(const f32x4*)(qr + jj);
                y[jj]   += xf * qv[0];
                y[jj+1] += xf * qv[1];
                y[jj+2] += xf * qv[2];
                y[jj+3] += xf * qv[3];
            }
        }
    }
    unsigned short* yo = Ytr + (size_t)t * FF * NN + n;
#pragma unroll
    for (int jj = 0; jj < 64; ++jj) yo[(size_t)jj * NN] = f2bf(y[jj]);
}

// ---------------------------------------------------------------------------
// K_D: out[t] = relu(A[t] @ Y[t]) via bf16 MFMA.
// 512 blocks (XCD-grouped: each XCD owns 4 consecutive timesteps), 256 thr.
// Block: 128 rows x 64 cols, K = 2048 in 64-chunks. XOR-swizzled LDS.
// ---------------------------------------------------------------------------
__global__ __launch_bounds__(256) void gemm_kernel(
    const float* __restrict__ A, const unsigned short* __restrict__ Ytr,
    float* __restrict__ out)
{
    __shared__ __align__(16) unsigned char Asm[128 * 64 * 2];  // bf16 [128 r][64 k]
    __shared__ __align__(16) unsigned char Bsm[64 * 64 * 2];   // bf16 [64 j][64 k]
    const int tid = threadIdx.x;
    // XCD-grouping remap: xcd = bid&7 gets timesteps [xcd*4, xcd*4+4)
    const int bid = blockIdx.x;
    const int xcd = bid & 7, li = bid >> 3;
    const int t = (xcd << 2) + (li >> 4);
    const int m0 = (li & 15) * 128;
    const int lane = tid & 63, w = tid >> 6;
    const int lr = lane & 15, lk = (lane >> 4) << 3;

    const float* Ap = A + (size_t)t * NN * NN + (size_t)m0 * NN;
    const unsigned short* Yp = Ytr + (size_t)t * FF * NN;

    f32x4 acc[2][4];
#pragma unroll
    for (int mt = 0; mt < 2; ++mt)
#pragma unroll
        for (int nt = 0; nt < 4; ++nt) acc[mt][nt] = (f32x4){0.f, 0.f, 0.f, 0.f};

    for (int kk = 0; kk < NN; kk += 64) {
        __syncthreads();
        // stage A tile: 128x64 f32 -> bf16, swizzled
#pragma unroll
        for (int it = 0; it < 8; ++it) {
            const int c = tid + it * 256;
            const int r = c >> 4;
            const int c4 = (c & 15) << 2;
            const float4 v = *(const float4*)(Ap + (size_t)r * NN + kk + c4);
            ushort4 pk = make_ushort4(f2bf(v.x), f2bf(v.y), f2bf(v.z), f2bf(v.w));
            int byte = (r << 7) + (c4 << 1);
            byte ^= (r & 7) << 4;
            *(ushort4*)(Asm + byte) = pk;
        }
        // stage B tile: Ytr[j][kk..kk+64], swizzled
#pragma unroll
        for (int it = 0; it < 2; ++it) {
            const int c = tid + it * 256;
            const int j = c >> 3;
            const int c8 = (c & 7) << 3;
            const uint4 v = *(const uint4*)(Yp + (size_t)j * NN + kk + c8);
            int byte = (j << 7) + (c8 << 1);
            byte ^= (j & 7) << 4;
            *(uint4*)(Bsm + byte) = v;
        }
        __syncthreads();
#pragma unroll
        for (int kt = 0; kt < 2; ++kt) {
            bf16x8 af[2], bfv[4];
#pragma unroll
            for (int mt = 0; mt < 2; ++mt) {
                const int row = (w << 5) + (mt << 4) + lr;
                const int k = (kt << 5) + lk;
                int byte = (row << 7) + (k << 1);
                byte ^= (row & 7) << 4;
                af[mt] = *(const bf16x8*)(Asm + byte);
            }
#pragma unroll
            for (int nt = 0; nt < 4; ++nt) {
                const int j = (nt << 4) + lr;
                const int k = (kt << 5) + lk;
                int byte = (j << 7) + (k << 1);
                byte ^= (j & 7) << 4;
                bfv[nt] = *(const bf16x8*)(Bsm + byte);
            }
#pragma unroll
            for (int mt = 0; mt < 2; ++mt)
#pragma unroll
                for (int nt = 0; nt < 4; ++nt)
                    acc[mt][nt] = __builtin_amdgcn_mfma_f32_16x16x32_bf16(
                        af[mt], bfv[nt], acc[mt][nt], 0, 0, 0);
        }
    }
    // store: D col = lane&15, row = (lane>>4)*4 + reg
#pragma unroll
    for (int mt = 0; mt < 2; ++mt)
#pragma unroll
        for (int nt = 0; nt < 4; ++nt) {
            const int row0 = m0 + (w << 5) + (mt << 4) + ((lane >> 4) << 2);
            const int col = (nt << 4) + lr;
#pragma unroll
            for (int rg = 0; rg < 4; ++rg) {
                const float v = acc[mt][nt][rg];
                out[((size_t)t * NN + (row0 + rg)) * FF + col] = v > 0.f ? v : 0.f;
            }
        }
}

// ---------------------------------------------------------------------------
extern "C" void kernel_launch(void* const* d_in, const int* in_sizes, int n_in,
                              void* d_out, int out_size, void* d_ws, size_t ws_size,
                              hipStream_t stream) {
    const float* A      = (const float*)d_in[0];
    const float* X      = (const float*)d_in[1];
    const float* mask   = (const float*)d_in[2];
    const float* Q0     = (const float*)d_in[3];
    const float* scorer = (const float*)d_in[4];
    const float* Wu     = (const float*)d_in[5];
    const float* Uu     = (const float*)d_in[6];
    const float* bu     = (const float*)d_in[7];
    const float* Wr     = (const float*)d_in[8];
    const float* Ur     = (const float*)d_in[9];
    const float* br     = (const float*)d_in[10];
    const float* Wh     = (const float*)d_in[11];
    const float* Uh     = (const float*)d_in[12];
    const float* bh     = (const float*)d_in[13];
    float* out = (float*)d_out;

    float* ws   = (float*)d_ws;
    float* zt   = ws;              // [T][64][64]
    float* Wz   = ws + 131072;     // [3][T][64][64]
    float* Qseq = ws + 524288;     // [T][64][64]
    unsigned short* Ytr = (unsigned short*)(ws + 655360);  // [T][64][2048] bf16

    topk_kernel<<<TT, 256, 0, stream>>>(X, mask, scorer, zt);
    wz_kernel<<<dim3(3, TT), 256, 0, stream>>>(zt, Wu, bu, Wr, br, Wh, bh, Wz);
    qchain_kernel<<<FF, 256, 0, stream>>>(Q0, Uu, Ur, Uh, Wz, Qseq);
    y_kernel<<<dim3(NN / 256, TT), 256, 0, stream>>>(X, Qseq, Ytr);
    gemm_kernel<<<512, 256, 0, stream>>>(A, Ytr, out);
}